// Round 1
// 115.384 us; speedup vs baseline: 1.0650x; 1.0650x over previous
//
#include <hip/hip_runtime.h>
#include <math.h>

#define N_ 2
#define L_ 2048
#define S_ 2048
#define H_ 8
#define D_ 64

#define BLK_L 256        // l-rows per block (4 waves x 64)
#define BS 64            // s-rows per K tile
#define SSPLIT 4         // z-split over S

typedef __attribute__((ext_vector_type(8))) short short8;
typedef __attribute__((ext_vector_type(4))) float floatx4;

__device__ __forceinline__ float feat(float x) {
    // elu(x)+1 = x>0 ? x+1 : exp(x)
    return x > 0.0f ? x + 1.0f : __expf(x);
}
__device__ __forceinline__ short f2bf(float x) {
    unsigned u = __float_as_uint(x);
    unsigned r = (u + 0x7fffu + ((u >> 16) & 1u)) >> 16;   // round-nearest-even
    return (short)r;
}
__device__ __forceinline__ float bf2f(short h) {
    return __uint_as_float(((unsigned)(unsigned short)h) << 16);
}
__device__ __forceinline__ void gload_lds16(const void* g, void* l) {
    // 16B direct global->LDS DMA; LDS dest is wave-uniform base + lane*16
    __builtin_amdgcn_global_load_lds(
        (__attribute__((address_space(1))) void*)g,
        (__attribute__((address_space(3))) void*)l, 16, 0, 0);
}

// -------------------------------------------------------------------------
// featk: featurize K once -> bf16 hi/lo planes [n][h][s][64], slot-swizzled
// (16B slot c of row s stored at slot c ^ (s&7)) so a LINEAR global_load_lds
// copy yields a bank-conflict-free swizzled LDS tile. Fuses the Ksum reduce.
// -------------------------------------------------------------------------
__global__ __launch_bounds__(256) void featk_kernel(
        const float* __restrict__ K, const float* __restrict__ kvmask,
        short* __restrict__ Khi, short* __restrict__ Klo,
        float* __restrict__ Ksum) {
    __shared__ float sm[64][68];           // +4 pad: conflict-light stores
    int nh = blockIdx.x;                   // 16
    int z  = blockIdx.y;                   // 32 chunks of 64 s-rows
    int n = nh >> 3, h = nh & 7;
    int t = threadIdx.x;
    int srow = t >> 2, g = t & 3;          // thread covers d in [g*16, g*16+16)
    int s = z * 64 + srow;

    float km = kvmask[n * S_ + s];
    const float* kp = K + (((size_t)n * S_ + s) * H_ + h) * D_ + g * 16;
    float fv[16];
    #pragma unroll
    for (int j = 0; j < 4; ++j) {
        float4 v = *(const float4*)(kp + j * 4);
        fv[4 * j + 0] = feat(v.x) * km;
        fv[4 * j + 1] = feat(v.y) * km;
        fv[4 * j + 2] = feat(v.z) * km;
        fv[4 * j + 3] = feat(v.w) * km;
    }
    short8 h0, h1, l0, l1;
    #pragma unroll
    for (int j = 0; j < 8; ++j) {
        short hb = f2bf(fv[j]);
        h0[j] = hb;  l0[j] = f2bf(fv[j] - bf2f(hb));
        short hb2 = f2bf(fv[8 + j]);
        h1[j] = hb2; l1[j] = f2bf(fv[8 + j] - bf2f(hb2));
    }
    size_t rowbase = ((size_t)nh * S_ + s) * (size_t)D_;   // shorts
    int rx = srow & 7;
    // chunks 2g and 2g+1, swizzled slot = chunk ^ (s&7)
    *(short8*)(Khi + rowbase + ((((2 * g)    ) ^ rx) << 3)) = h0;
    *(short8*)(Khi + rowbase + ((((2 * g) + 1) ^ rx) << 3)) = h1;
    *(short8*)(Klo + rowbase + ((((2 * g)    ) ^ rx) << 3)) = l0;
    *(short8*)(Klo + rowbase + ((((2 * g) + 1) ^ rx) << 3)) = l1;

    // ---- fused Ksum: sum over this block's 64 s-rows, atomicAdd once ----
    #pragma unroll
    for (int j2 = 0; j2 < 4; ++j2)
        *(float4*)&sm[srow][g * 16 + 4 * j2] =
            make_float4(fv[4 * j2], fv[4 * j2 + 1], fv[4 * j2 + 2], fv[4 * j2 + 3]);
    __syncthreads();
    if (t < 64) {
        float tot = 0.f;
        #pragma unroll
        for (int r = 0; r < 64; ++r) tot += sm[r][t];
        atomicAdd(&Ksum[nh * 64 + t], tot);
    }
}

// -------------------------------------------------------------------------
// rowmax: MFMA over prefeaturized bf16 hi/lo K planes.
// Staging = double-buffered global_load_lds (16B), 2-phase pipeline,
// one barrier per tile. ds_read uses the same XOR swizzle -> conflict-free.
// -------------------------------------------------------------------------
__global__ __launch_bounds__(256) void rowmax_mfma(
        const float* __restrict__ Q, const short* __restrict__ Khi,
        const short* __restrict__ Klo, const float* __restrict__ qmask,
        float* __restrict__ rowmaxg) {
    __shared__ __align__(16) char lds[2][16384];   // [dbuf][hi 8KB | lo 8KB]

    // Bijective XCD swizzle (m204): group the 8 lblocks sharing a (nh,z)
    // K-slice onto one XCD's L2. grid = (8,16,4) -> 512 wgs, 64 per XCD.
    int flat = blockIdx.x + (blockIdx.y << 3) + (blockIdx.z << 7);
    int nid  = ((flat & 7) << 6) | (flat >> 3);
    int bx = nid & 7;            // lblock index
    int nh = (nid >> 3) & 15;    // (n,h)
    int z  = nid >> 7;           // s-split

    int n = nh >> 3, h = nh & 7;
    int t = threadIdx.x;
    int w = t >> 6, lane = t & 63;
    int quad = lane >> 4, l16 = lane & 15;
    int lblock = bx * BLK_L;

    const char* gKh = (const char*)Khi + ((size_t)nh * S_ + (size_t)z * (S_ / SSPLIT)) * 128;
    const char* gKl = (const char*)Klo + ((size_t)nh * S_ + (size_t)z * (S_ / SSPLIT)) * 128;
    int sidx = w << 2;   // this wave's 4 copy-chunk ids (waves 0-1: hi, 2-3: lo)

    auto stage = [&](int tile, int db) {
        #pragma unroll
        for (int c = 0; c < 4; ++c) {
            int idx = sidx | c;                              // 0..15
            const char* src = (idx < 8 ? gKh : gKl)
                              + tile * 8192 + ((idx & 7) << 10) + (lane << 4);
            gload_lds16(src, &lds[db][idx << 10]);
        }
    };

    stage(0, 0);   // tile 0 in flight while we featurize Q below

    // ---- A fragments: featurized Q, bf16 hi/lo split, in registers ----
    // A-frag layout (16x16x32): m = lane&15, k = quad*8 + j
    short8 Ah[4][2], Al[4][2];
    #pragma unroll
    for (int lsub = 0; lsub < 4; ++lsub) {
        int lrow = lblock + w * 64 + lsub * 16 + l16;
        float qm = qmask[n * L_ + lrow];
        const float* qp = Q + (((size_t)n * L_ + lrow) * H_ + h) * D_ + quad * 8;
        #pragma unroll
        for (int ks = 0; ks < 2; ++ks) {
            float4 v0 = *(const float4*)(qp + ks * 32);
            float4 v1 = *(const float4*)(qp + ks * 32 + 4);
            float fv[8];
            fv[0] = feat(v0.x) * qm; fv[1] = feat(v0.y) * qm;
            fv[2] = feat(v0.z) * qm; fv[3] = feat(v0.w) * qm;
            fv[4] = feat(v1.x) * qm; fv[5] = feat(v1.y) * qm;
            fv[6] = feat(v1.z) * qm; fv[7] = feat(v1.w) * qm;
            short8 hi, lo;
            #pragma unroll
            for (int j = 0; j < 8; ++j) {
                short hb = f2bf(fv[j]);
                hi[j] = hb;
                lo[j] = f2bf(fv[j] - bf2f(hb));
            }
            Ah[lsub][ks] = hi;
            Al[lsub][ks] = lo;
        }
    }

    // B-frag LDS byte offsets (constant per thread): row = ssub*16+l16,
    // 16B slot c read at swizzled slot c ^ (row&7)
    int boff[4][2];
    #pragma unroll
    for (int ssub = 0; ssub < 4; ++ssub) {
        int row = ssub * 16 + l16;
        int rx = l16 & 7;
        boff[ssub][0] = row * 128 + ((quad ^ rx) << 4);
        boff[ssub][1] = row * 128 + (((quad + 4) ^ rx) << 4);
    }

    float rmax[4][4];
    #pragma unroll
    for (int i = 0; i < 4; ++i)
        #pragma unroll
        for (int r = 0; r < 4; ++r) rmax[i][r] = 0.f;   // dots >= 0

    __syncthreads();   // drains stage(0) vmcnt + barrier

    const int tiles = S_ / SSPLIT / BS;    // 8
    for (int tile = 0; tile < tiles; ++tile) {
        int db = tile & 1;
        if (tile + 1 < tiles) stage(tile + 1, db ^ 1);   // prefetch next tile
        const char* hp = lds[db];
        const char* lp = lds[db] + 8192;
        #pragma unroll
        for (int ssub = 0; ssub < 4; ++ssub) {
            // B-frag layout: s-row = lane&15, k = quad*8 + j
            short8 Bh0 = *(const short8*)(hp + boff[ssub][0]);
            short8 Bh1 = *(const short8*)(hp + boff[ssub][1]);
            short8 Bl0 = *(const short8*)(lp + boff[ssub][0]);
            short8 Bl1 = *(const short8*)(lp + boff[ssub][1]);
            #pragma unroll
            for (int lsub = 0; lsub < 4; ++lsub) {
                floatx4 acc = {0.f, 0.f, 0.f, 0.f};
                acc = __builtin_amdgcn_mfma_f32_16x16x32_bf16(Ah[lsub][0], Bh0, acc, 0, 0, 0);
                acc = __builtin_amdgcn_mfma_f32_16x16x32_bf16(Ah[lsub][1], Bh1, acc, 0, 0, 0);
                acc = __builtin_amdgcn_mfma_f32_16x16x32_bf16(Ah[lsub][0], Bl0, acc, 0, 0, 0);
                acc = __builtin_amdgcn_mfma_f32_16x16x32_bf16(Ah[lsub][1], Bl1, acc, 0, 0, 0);
                acc = __builtin_amdgcn_mfma_f32_16x16x32_bf16(Al[lsub][0], Bh0, acc, 0, 0, 0);
                acc = __builtin_amdgcn_mfma_f32_16x16x32_bf16(Al[lsub][1], Bh1, acc, 0, 0, 0);
                #pragma unroll
                for (int r = 0; r < 4; ++r)
                    rmax[lsub][r] = fmaxf(rmax[lsub][r], acc[r]);
            }
        }
        __syncthreads();   // reads done + prefetched loads landed
    }

    // ---- epilogue: reduce rowmax across the 16 column-lanes, atomicMax ----
    // C/D layout: col(s) = lane&15, row(l) = quad*4 + r
    #pragma unroll
    for (int lsub = 0; lsub < 4; ++lsub)
        #pragma unroll
        for (int r = 0; r < 4; ++r) {
            float m = rmax[lsub][r];
            m = fmaxf(m, __shfl_xor(m, 1, 64));
            m = fmaxf(m, __shfl_xor(m, 2, 64));
            m = fmaxf(m, __shfl_xor(m, 4, 64));
            m = fmaxf(m, __shfl_xor(m, 8, 64));
            if (l16 == 0) {
                int l = lblock + w * 64 + lsub * 16 + quad * 4 + r;
                atomicMax((unsigned*)&rowmaxg[(size_t)nh * L_ + l],
                          __float_as_uint(m));
            }
        }
}

__global__ __launch_bounds__(256) void finalize_kernel(
        const float* __restrict__ Q, const float* __restrict__ qmask,
        const float* __restrict__ Ksum, const float* __restrict__ rowmaxg,
        const float* __restrict__ W, const float* __restrict__ b,
        float* __restrict__ out) {
    int t = threadIdx.x;
    int lane = t & 63;
    int wid = (blockIdx.x << 2) | (t >> 6);    // global (n,l,h) index
    int n = wid / (L_ * H_);
    int lh = wid % (L_ * H_);
    int l = lh / H_, h = lh % H_;

    float q = Q[(size_t)wid * 64 + lane];
    float qm = qmask[n * L_ + l];
    float p = feat(q) * qm * Ksum[(n * H_ + h) * 64 + lane];
    #pragma unroll
    for (int off = 32; off > 0; off >>= 1)
        p += __shfl_xor(p, off, 64);
    float mean = p * (1.0f / S_);
    float mx = rowmaxg[((size_t)n * H_ + h) * L_ + l];
    float zz = W[0] * mean + W[1] * mx + b[0];
    float g = 1.0f / (1.0f + __expf(-zz));
    out[(size_t)wid * 64 + lane] = q * qm * g;
}

extern "C" void kernel_launch(void* const* d_in, const int* in_sizes, int n_in,
                              void* d_out, int out_size, void* d_ws, size_t ws_size,
                              hipStream_t stream) {
    const float* Q      = (const float*)d_in[0];
    const float* K      = (const float*)d_in[1];
    // d_in[2] = values: masked in reference but unused downstream
    const float* qmask  = (const float*)d_in[3];
    const float* kvmask = (const float*)d_in[4];
    const float* W      = (const float*)d_in[5];
    const float* b      = (const float*)d_in[6];
    float* out = (float*)d_out;

    float* Ksum   = (float*)d_ws;                        // 1024 floats
    float* rowmax = (float*)d_ws + 1024;                 // 32768 floats
    short* Khi    = (short*)((float*)d_ws + 1024 + 32768);   // 4 MB, 16B-aligned
    short* Klo    = Khi + (size_t)N_ * H_ * S_ * D_;         // 4 MB

    // single memset covers Ksum + rowmax (adjacent)
    hipMemsetAsync(d_ws, 0, (1024 + (size_t)N_ * H_ * L_) * sizeof(float), stream);

    featk_kernel<<<dim3(N_ * H_, S_ / 64), 256, 0, stream>>>(K, kvmask, Khi, Klo, Ksum);
    rowmax_mfma<<<dim3(L_ / BLK_L, N_ * H_, SSPLIT), 256, 0, stream>>>(
        Q, Khi, Klo, qmask, rowmax);
    finalize_kernel<<<dim3(N_ * L_ * H_ / 4), 256, 0, stream>>>(
        Q, qmask, Ksum, rowmax, W, b, out);
}